// Round 4
// baseline (791.631 us; speedup 1.0000x reference)
//
#include <hip/hip_runtime.h>
#include <hip/hip_bf16.h>

#define NN 50000
#define NE 800000

typedef unsigned short u16;
typedef unsigned int   u32;

typedef __attribute__((ext_vector_type(8))) __bf16 bf16x8;
typedef __attribute__((ext_vector_type(4))) float  f32x4;

__device__ __forceinline__ float bf2f(u16 x) {
    u32 u = ((u32)x) << 16;
    return __builtin_bit_cast(float, u);
}
__device__ __forceinline__ u16 f2bf(float f) {
    u32 u = __builtin_bit_cast(u32, f);
    u32 r = (u + 0x7FFFu + ((u >> 16) & 1u)) >> 16;
    return (u16)r;
}

// ---------------- graph preprocessing ----------------

__global__ __launch_bounds__(256) void count_k(const int* __restrict__ dst, int* __restrict__ deg, int E) {
    int e = blockIdx.x * 256 + threadIdx.x;
    if (e < E) atomicAdd(&deg[dst[e]], 1);
}

__global__ __launch_bounds__(256) void dinv_k(const int* __restrict__ deg, float* __restrict__ dinv, int n) {
    int i = blockIdx.x * 256 + threadIdx.x;
    if (i < n) dinv[i] = rsqrtf((float)deg[i] + 1.0f);
}

__global__ __launch_bounds__(256) void scan1_k(const int* __restrict__ deg, int* __restrict__ bsum, int n) {
    __shared__ int sd[256];
    int i = blockIdx.x * 256 + threadIdx.x;
    sd[threadIdx.x] = (i < n) ? deg[i] : 0;
    __syncthreads();
    for (int s = 128; s > 0; s >>= 1) {
        if (threadIdx.x < s) sd[threadIdx.x] += sd[threadIdx.x + s];
        __syncthreads();
    }
    if (threadIdx.x == 0) bsum[blockIdx.x] = sd[0];
}

__global__ __launch_bounds__(256) void scan2_k(int* __restrict__ bsum, int nb) {
    __shared__ int sd[256];
    int t = threadIdx.x;
    int v = (t < nb) ? bsum[t] : 0;
    sd[t] = v;
    __syncthreads();
    for (int off = 1; off < 256; off <<= 1) {
        int tv = (t >= off) ? sd[t - off] : 0;
        __syncthreads();
        sd[t] += tv;
        __syncthreads();
    }
    if (t < nb) bsum[t] = sd[t] - v;  // exclusive
}

__global__ __launch_bounds__(256) void scan3_k(const int* __restrict__ deg, const int* __restrict__ bofs,
                                               int* __restrict__ rs, int* __restrict__ cur, int n) {
    __shared__ int sd[256];
    int t = threadIdx.x;
    int i = blockIdx.x * 256 + t;
    int v = (i < n) ? deg[i] : 0;
    sd[t] = v;
    __syncthreads();
    for (int off = 1; off < 256; off <<= 1) {
        int tv = (t >= off) ? sd[t - off] : 0;
        __syncthreads();
        sd[t] += tv;
        __syncthreads();
    }
    int excl = sd[t] - v + bofs[blockIdx.x];
    if (i < n) { rs[i] = excl; cur[i] = excl; }
}

__global__ __launch_bounds__(256) void fill_k(const int* __restrict__ src, const int* __restrict__ dst,
                                              int* __restrict__ cur, int* __restrict__ csr, int E) {
    int e = blockIdx.x * 256 + threadIdx.x;
    if (e < E) {
        int d = dst[e];
        int pos = atomicAdd(&cur[d], 1);
        csr[pos] = src[e];
    }
}

// ---------------- weight transpose+cast: W f32[K][F] -> Wt bf16[F][K] ----------------

__global__ __launch_bounds__(256) void transpose_k(const float* __restrict__ W, u16* __restrict__ Wt, int K, int F) {
    __shared__ float t[32][33];
    int k0 = blockIdx.x * 32, f0 = blockIdx.y * 32;
    int tx = threadIdx.x & 31, ty = threadIdx.x >> 5;
    for (int r = ty; r < 32; r += 8) t[r][tx] = W[(size_t)(k0 + r) * F + f0 + tx];
    __syncthreads();
    for (int r = ty; r < 32; r += 8) Wt[(size_t)(f0 + r) * K + k0 + tx] = f2bf(t[tx][r]);
}

// ---------------- aggregations (pull, CSR by dst) ----------------
// agg1: X f32[N,256] -> Y bf16[N,256]

__global__ __launch_bounds__(256) void agg1_k(const float* __restrict__ X, u16* __restrict__ Y,
                                              const float* __restrict__ dinv, const int* __restrict__ rs,
                                              const int* __restrict__ dg, const int* __restrict__ csr) {
    const int i = blockIdx.x;
    const int tid = threadIdx.x;
    const int start = rs[i];
    const int cnt = dg[i];
    const float di = dinv[i];
    __shared__ int s_idx[64];
    __shared__ float s_w[64];

    float a = di * X[(size_t)i * 256 + tid];

    for (int base = 0; base < cnt; base += 64) {
        const int m = min(64, cnt - base);
        __syncthreads();
        if (tid < m) {
            int s = csr[start + base + tid];
            s_idx[tid] = s;
            s_w[tid] = dinv[s];
        }
        __syncthreads();
        for (int jj = 0; jj < m; jj++)
            a += s_w[jj] * X[(size_t)s_idx[jj] * 256 + tid];
    }
    Y[(size_t)i * 256 + tid] = f2bf(a * di);
}

// agg2: X bf16[N,512] -> Y bf16[N,512], 2 feats/thread

__global__ __launch_bounds__(256) void agg2_k(const u16* __restrict__ X, u16* __restrict__ Y,
                                              const float* __restrict__ dinv, const int* __restrict__ rs,
                                              const int* __restrict__ dg, const int* __restrict__ csr) {
    const int i = blockIdx.x;
    const int tid = threadIdx.x;
    const int start = rs[i];
    const int cnt = dg[i];
    const float di = dinv[i];
    __shared__ int s_idx[64];
    __shared__ float s_w[64];

    u32 p = *(const u32*)(X + (size_t)i * 512 + tid * 2);
    float a0 = di * bf2f((u16)p);
    float a1 = di * bf2f((u16)(p >> 16));

    for (int base = 0; base < cnt; base += 64) {
        const int m = min(64, cnt - base);
        __syncthreads();
        if (tid < m) {
            int s = csr[start + base + tid];
            s_idx[tid] = s;
            s_w[tid] = dinv[s];
        }
        __syncthreads();
        for (int jj = 0; jj < m; jj++) {
            u32 q = *(const u32*)(X + (size_t)s_idx[jj] * 512 + tid * 2);
            a0 += s_w[jj] * bf2f((u16)q);
            a1 += s_w[jj] * bf2f((u16)(q >> 16));
        }
    }
    a0 *= di; a1 *= di;
    *(u32*)(Y + (size_t)i * 512 + tid * 2) = ((u32)f2bf(a1) << 16) | (u32)f2bf(a0);
}

// agg3: G3 bf16[N,256] -> out f32[N,256], += b3 + x (both f32)

__global__ __launch_bounds__(256) void agg3_k(const u16* __restrict__ G3, float* __restrict__ out,
                                              const float* __restrict__ dinv, const int* __restrict__ rs,
                                              const int* __restrict__ dg, const int* __restrict__ csr,
                                              const float* __restrict__ b3, const float* __restrict__ x) {
    const int i = blockIdx.x;
    const int tid = threadIdx.x;
    const int start = rs[i];
    const int cnt = dg[i];
    const float di = dinv[i];
    __shared__ int s_idx[64];
    __shared__ float s_w[64];

    float a = di * bf2f(G3[(size_t)i * 256 + tid]);

    for (int base = 0; base < cnt; base += 64) {
        const int m = min(64, cnt - base);
        __syncthreads();
        if (tid < m) {
            int s = csr[start + base + tid];
            s_idx[tid] = s;
            s_w[tid] = dinv[s];
        }
        __syncthreads();
        for (int jj = 0; jj < m; jj++)
            a += s_w[jj] * bf2f(G3[(size_t)s_idx[jj] * 256 + tid]);
    }
    out[(size_t)i * 256 + tid] = a * di + b3[tid] + x[(size_t)i * 256 + tid];
}

// ---------------- bf16 MFMA GEMM: C[M][F] = A[M][K] @ Wt[F][K]^T (+bias f32, +col stats) ----
// 128x128 tile, BK=32, 4 waves each 64x64 (4x4 of 16x16x32 MFMA). C bf16 out.

template <bool STATS, bool BIAS>
__global__ __launch_bounds__(256) void gemm_k(const u16* __restrict__ A, const u16* __restrict__ Wt,
                                              const float* __restrict__ bias, u16* __restrict__ C,
                                              float* __restrict__ colsum, float* __restrict__ colsq,
                                              int M, int K, int F) {
    __shared__ u16 As[128 * 40];
    __shared__ u16 Bs[128 * 40];
    const int m0 = blockIdx.x * 128, f0 = blockIdx.y * 128;
    const int tid = threadIdx.x;
    const int lane = tid & 63, wave = tid >> 6;
    const int waveM = (wave >> 1) * 64, waveN = (wave & 1) * 64;
    const int lrow = tid >> 2, lch = tid & 3;

    f32x4 acc[4][4];
    const f32x4 fz = {0.f, 0.f, 0.f, 0.f};
    #pragma unroll
    for (int i = 0; i < 4; i++)
        #pragma unroll
        for (int j = 0; j < 4; j++) acc[i][j] = fz;

    const int rA0 = m0 + lrow, rA1 = m0 + 64 + lrow;
    const u16* pA0 = A + (size_t)rA0 * K + lch * 8;
    const u16* pA1 = A + (size_t)rA1 * K + lch * 8;
    const u16* pB0 = Wt + (size_t)(f0 + lrow) * K + lch * 8;
    const u16* pB1 = Wt + (size_t)(f0 + 64 + lrow) * K + lch * 8;
    u16* qA0 = &As[lrow * 40 + lch * 8];
    u16* qA1 = &As[(64 + lrow) * 40 + lch * 8];
    u16* qB0 = &Bs[lrow * 40 + lch * 8];
    u16* qB1 = &Bs[(64 + lrow) * 40 + lch * 8];
    const uint4 z4 = {0u, 0u, 0u, 0u};

    const int fm = lane & 15, fq = lane >> 4;

    for (int k0 = 0; k0 < K; k0 += 32) {
        uint4 a0 = (rA0 < M) ? *(const uint4*)(pA0 + k0) : z4;
        uint4 a1 = (rA1 < M) ? *(const uint4*)(pA1 + k0) : z4;
        uint4 b0 = *(const uint4*)(pB0 + k0);
        uint4 b1 = *(const uint4*)(pB1 + k0);
        __syncthreads();
        *(uint4*)qA0 = a0;
        *(uint4*)qA1 = a1;
        *(uint4*)qB0 = b0;
        *(uint4*)qB1 = b1;
        __syncthreads();
        bf16x8 af[4], bfr[4];
        #pragma unroll
        for (int i = 0; i < 4; i++)
            af[i] = *(const bf16x8*)&As[(waveM + i * 16 + fm) * 40 + fq * 8];
        #pragma unroll
        for (int j = 0; j < 4; j++)
            bfr[j] = *(const bf16x8*)&Bs[(waveN + j * 16 + fm) * 40 + fq * 8];
        #pragma unroll
        for (int i = 0; i < 4; i++)
            #pragma unroll
            for (int j = 0; j < 4; j++)
                acc[i][j] = __builtin_amdgcn_mfma_f32_16x16x32_bf16(af[i], bfr[j], acc[i][j], 0, 0, 0);
    }

    // C/D layout: col=lane&15, row=(lane>>4)*4+reg  [learn_hip m89/m91]
    #pragma unroll
    for (int j = 0; j < 4; j++) {
        const int col = f0 + waveN + j * 16 + fm;
        const float bcol = BIAS ? bias[col] : 0.f;
        float s = 0.f, s2 = 0.f;
        #pragma unroll
        for (int i = 0; i < 4; i++) {
            const int rb = m0 + waveM + i * 16 + fq * 4;
            #pragma unroll
            for (int r = 0; r < 4; r++) {
                const int row = rb + r;
                if (row < M) {
                    float v = acc[i][j][r] + bcol;
                    C[(size_t)row * F + col] = f2bf(v);
                    if (STATS) { s += v; s2 += v * v; }
                }
            }
        }
        if (STATS) {
            s += __shfl_xor(s, 16);
            s += __shfl_xor(s, 32);
            s2 += __shfl_xor(s2, 16);
            s2 += __shfl_xor(s2, 32);
            if (fq == 0) {
                atomicAdd(&colsum[col], s);
                atomicAdd(&colsq[col], s2);
            }
        }
    }
}

// ---------------- BN finalize + apply (H is bf16) ----------------

__global__ __launch_bounds__(256) void bnfin_k(const float* __restrict__ sum, const float* __restrict__ sq,
                                               const float* __restrict__ g, const float* __restrict__ be,
                                               float* __restrict__ scale, float* __restrict__ shift,
                                               int F, float invN) {
    int f = blockIdx.x * 256 + threadIdx.x;
    if (f < F) {
        float m = sum[f] * invN;
        float v = sq[f] * invN - m * m;
        float s = rsqrtf(v + 1e-5f) * g[f];
        scale[f] = s;
        shift[f] = be[f] - m * s;
    }
}

__global__ __launch_bounds__(256) void bnrelu_k(u16* __restrict__ H, const float* __restrict__ scale,
                                                const float* __restrict__ shift, int total, int F) {
    int idx = blockIdx.x * 256 + threadIdx.x;
    int base = idx * 8;
    if (base >= total) return;
    uint4 p = *(const uint4*)(H + base);
    int col = base & (F - 1);
    u32 w[4] = {p.x, p.y, p.z, p.w};
    u32 o[4];
    #pragma unroll
    for (int q = 0; q < 4; q++) {
        float x0 = bf2f((u16)w[q]) * scale[col + 2 * q] + shift[col + 2 * q];
        float x1 = bf2f((u16)(w[q] >> 16)) * scale[col + 2 * q + 1] + shift[col + 2 * q + 1];
        x0 = fmaxf(x0, 0.f);
        x1 = fmaxf(x1, 0.f);
        o[q] = ((u32)f2bf(x1) << 16) | (u32)f2bf(x0);
    }
    uint4 po = {o[0], o[1], o[2], o[3]};
    *(uint4*)(H + base) = po;
}

// ---------------- launch ----------------

extern "C" void kernel_launch(void* const* d_in, const int* in_sizes, int n_in,
                              void* d_out, int out_size, void* d_ws, size_t ws_size,
                              hipStream_t stream) {
    const float* x   = (const float*)d_in[0];
    const int*   ei  = (const int*)d_in[1];
    const float* W1  = (const float*)d_in[2];
    const float* b1  = (const float*)d_in[3];
    const float* pg1 = (const float*)d_in[4];
    const float* pbe1= (const float*)d_in[5];
    const float* W2  = (const float*)d_in[6];
    const float* b2  = (const float*)d_in[7];
    const float* pg2 = (const float*)d_in[8];
    const float* pbe2= (const float*)d_in[9];
    const float* W3  = (const float*)d_in[10];
    const float* b3  = (const float*)d_in[11];
    float* out = (float*)d_out;

    char* ws = (char*)d_ws;
    size_t off = 0;
    auto alloc = [&](size_t bytes) -> char* {
        char* p = ws + off;
        off += (bytes + 255) & ~(size_t)255;
        return p;
    };
    float* dinv  = (float*)alloc(NN * 4);
    int*   deg   = (int*)alloc(NN * 4);
    int*   rs    = (int*)alloc(NN * 4);
    int*   cur   = (int*)alloc(NN * 4);
    int*   bsum  = (int*)alloc(256 * 4);
    int*   csr   = (int*)alloc(NE * 4);
    float* stats = (float*)alloc(4 * 512 * 4);
    float* cs1 = stats, *cq1 = stats + 512, *cs2 = stats + 1024, *cq2 = stats + 1536;
    float* scale = (float*)alloc(512 * 4);
    float* shift = (float*)alloc(512 * 4);
    u16*   W1t   = (u16*)alloc((size_t)512 * 256 * 2);
    u16*   W2t   = (u16*)alloc((size_t)512 * 512 * 2);
    u16*   W3t   = (u16*)alloc((size_t)256 * 512 * 2);
    u16*   HB    = (u16*)alloc((size_t)NN * 512 * 2);   // 51.2 MB
    u16*   G3    = (u16*)alloc((size_t)NN * 256 * 2);   // 25.6 MB  (total ws ~82 MB)

    u16* A1 = (u16*)d_out;   // bf16 scratch [N,256] in d_out (25.6 of 51.2 MB)
    u16* A2 = (u16*)d_out;   // bf16 scratch [N,512] in d_out (full 51.2 MB)

    const int* srcp = ei;
    const int* dstp = ei + NE;

    hipMemsetAsync(deg, 0, NN * 4, stream);
    hipMemsetAsync(stats, 0, 4 * 512 * 4, stream);

    const int nbN = (NN + 255) / 256;
    count_k<<<(NE + 255) / 256, 256, 0, stream>>>(dstp, deg, NE);
    dinv_k<<<nbN, 256, 0, stream>>>(deg, dinv, NN);
    scan1_k<<<nbN, 256, 0, stream>>>(deg, bsum, NN);
    scan2_k<<<1, 256, 0, stream>>>(bsum, nbN);
    scan3_k<<<nbN, 256, 0, stream>>>(deg, bsum, rs, cur, NN);
    fill_k<<<(NE + 255) / 256, 256, 0, stream>>>(srcp, dstp, cur, csr, NE);

    transpose_k<<<dim3(256 / 32, 512 / 32), 256, 0, stream>>>(W1, W1t, 256, 512);
    transpose_k<<<dim3(512 / 32, 512 / 32), 256, 0, stream>>>(W2, W2t, 512, 512);
    transpose_k<<<dim3(512 / 32, 256 / 32), 256, 0, stream>>>(W3, W3t, 512, 256);

    const int MT = (NN + 127) / 128;  // 391

    // Layer 1: A1 = Agg(x) [bf16, in d_out]; H1 = A1@W1 + b1 -> HB [bf16]; BN+ReLU in place
    agg1_k<<<NN, 256, 0, stream>>>(x, A1, dinv, rs, deg, csr);
    gemm_k<true, true><<<dim3(MT, 4), 256, 0, stream>>>(A1, W1t, b1, HB, cs1, cq1, NN, 256, 512);
    bnfin_k<<<2, 256, 0, stream>>>(cs1, cq1, pg1, pbe1, scale, shift, 512, 1.f / NN);
    bnrelu_k<<<NN * 512 / 8 / 256, 256, 0, stream>>>(HB, scale, shift, NN * 512, 512);

    // Layer 2: A2 = Agg(H1) [bf16, full d_out]; H2 = A2@W2 + b2 -> HB; BN+ReLU
    agg2_k<<<NN, 256, 0, stream>>>(HB, A2, dinv, rs, deg, csr);
    gemm_k<true, true><<<dim3(MT, 4), 256, 0, stream>>>(A2, W2t, b2, HB, cs2, cq2, NN, 512, 512);
    bnfin_k<<<2, 256, 0, stream>>>(cs2, cq2, pg2, pbe2, scale, shift, 512, 1.f / NN);
    bnrelu_k<<<NN * 512 / 8 / 256, 256, 0, stream>>>(HB, scale, shift, NN * 512, 512);

    // Layer 3: G3 = H2@W3 [bf16, ws]; out = Agg(G3) + b3 + x  [f32, fills all of d_out]
    gemm_k<false, false><<<dim3(MT, 2), 256, 0, stream>>>(HB, W3t, nullptr, G3, nullptr, nullptr, NN, 512, 256);
    agg3_k<<<NN, 256, 0, stream>>>(G3, out, dinv, rs, deg, csr, b3, x);
}

// Round 6
// 712.782 us; speedup vs baseline: 1.1106x; 1.1106x over previous
//
#include <hip/hip_runtime.h>
#include <hip/hip_bf16.h>

#define NN 50000
#define NE 800000

typedef unsigned short u16;
typedef unsigned int   u32;

typedef __attribute__((ext_vector_type(8))) __bf16 bf16x8;
typedef __attribute__((ext_vector_type(4))) float  f32x4;

__device__ __forceinline__ float bf2f(u16 x) {
    u32 u = ((u32)x) << 16;
    return __builtin_bit_cast(float, u);
}
__device__ __forceinline__ u16 f2bf(float f) {
    u32 u = __builtin_bit_cast(u32, f);
    u32 r = (u + 0x7FFFu + ((u >> 16) & 1u)) >> 16;
    return (u16)r;
}
__device__ __forceinline__ float bflo(u32 w) { return __builtin_bit_cast(float, w << 16); }
__device__ __forceinline__ float bfhi(u32 w) { return __builtin_bit_cast(float, w & 0xffff0000u); }

// ---------------- graph preprocessing ----------------

__global__ __launch_bounds__(256) void count_k(const int* __restrict__ dst, int* __restrict__ deg, int E) {
    int e = blockIdx.x * 256 + threadIdx.x;
    if (e < E) atomicAdd(&deg[dst[e]], 1);
}

__global__ __launch_bounds__(256) void dinv_k(const int* __restrict__ deg, float* __restrict__ dinv, int n) {
    int i = blockIdx.x * 256 + threadIdx.x;
    if (i < n) dinv[i] = rsqrtf((float)deg[i] + 1.0f);
}

__global__ __launch_bounds__(256) void scan1_k(const int* __restrict__ deg, int* __restrict__ bsum, int n) {
    __shared__ int sd[256];
    int i = blockIdx.x * 256 + threadIdx.x;
    sd[threadIdx.x] = (i < n) ? deg[i] : 0;
    __syncthreads();
    for (int s = 128; s > 0; s >>= 1) {
        if (threadIdx.x < s) sd[threadIdx.x] += sd[threadIdx.x + s];
        __syncthreads();
    }
    if (threadIdx.x == 0) bsum[blockIdx.x] = sd[0];
}

__global__ __launch_bounds__(256) void scan2_k(int* __restrict__ bsum, int nb) {
    __shared__ int sd[256];
    int t = threadIdx.x;
    int v = (t < nb) ? bsum[t] : 0;
    sd[t] = v;
    __syncthreads();
    for (int off = 1; off < 256; off <<= 1) {
        int tv = (t >= off) ? sd[t - off] : 0;
        __syncthreads();
        sd[t] += tv;
        __syncthreads();
    }
    if (t < nb) bsum[t] = sd[t] - v;  // exclusive
}

__global__ __launch_bounds__(256) void scan3_k(const int* __restrict__ deg, const int* __restrict__ bofs,
                                               int* __restrict__ rs, int* __restrict__ cur, int n) {
    __shared__ int sd[256];
    int t = threadIdx.x;
    int i = blockIdx.x * 256 + t;
    int v = (i < n) ? deg[i] : 0;
    sd[t] = v;
    __syncthreads();
    for (int off = 1; off < 256; off <<= 1) {
        int tv = (t >= off) ? sd[t - off] : 0;
        __syncthreads();
        sd[t] += tv;
        __syncthreads();
    }
    int excl = sd[t] - v + bofs[blockIdx.x];
    if (i < n) { rs[i] = excl; cur[i] = excl; }
}

__global__ __launch_bounds__(256) void fill_k(const int* __restrict__ src, const int* __restrict__ dst,
                                              int* __restrict__ cur, int* __restrict__ csr, int E) {
    int e = blockIdx.x * 256 + threadIdx.x;
    if (e < E) {
        int d = dst[e];
        int pos = atomicAdd(&cur[d], 1);
        csr[pos] = src[e];
    }
}

// ---------------- x f32 -> bf16 cast ----------------

__global__ __launch_bounds__(256) void cast_k(const float* __restrict__ X, u16* __restrict__ Y, int total) {
    int idx = (blockIdx.x * 256 + threadIdx.x) * 8;
    if (idx >= total) return;
    float4 a = *(const float4*)(X + idx);
    float4 b = *(const float4*)(X + idx + 4);
    uint4 o;
    o.x = (u32)f2bf(a.x) | ((u32)f2bf(a.y) << 16);
    o.y = (u32)f2bf(a.z) | ((u32)f2bf(a.w) << 16);
    o.z = (u32)f2bf(b.x) | ((u32)f2bf(b.y) << 16);
    o.w = (u32)f2bf(b.z) | ((u32)f2bf(b.w) << 16);
    *(uint4*)(Y + idx) = o;
}

// ---------------- weight transpose+cast: W f32[K][F] -> Wt bf16[F][K] ----------------

__global__ __launch_bounds__(256) void transpose_k(const float* __restrict__ W, u16* __restrict__ Wt, int K, int F) {
    __shared__ float t[32][33];
    int k0 = blockIdx.x * 32, f0 = blockIdx.y * 32;
    int tx = threadIdx.x & 31, ty = threadIdx.x >> 5;
    for (int r = ty; r < 32; r += 8) t[r][tx] = W[(size_t)(k0 + r) * F + f0 + tx];
    __syncthreads();
    for (int r = ty; r < 32; r += 8) Wt[(size_t)(f0 + r) * K + k0 + tx] = f2bf(t[tx][r]);
}

// ---------------- unified GCN aggregation (pull, CSR by dst) ----------------
// Block = 4 waves; wave w handles edges jj ≡ w (mod 4); each wave's 64 lanes span the
// full F-wide row (FB = F/64 bf16 feats per lane, 8B or 16B loads). LDS merge at end.
// MODE 0: plain gather, bf16 out.        (agg1: XB -> A1)
// MODE 1: BN+ReLU applied to each gathered value (fused bnrelu), bf16 out. (agg2)
// MODE 2: plain gather + b3 + xres, f32 out.  (agg3, final layer)

template <int F, int MODE>
__global__ __launch_bounds__(256) void aggu_k(const u16* __restrict__ X, u16* __restrict__ Y,
                                              float* __restrict__ Yf,
                                              const float* __restrict__ dinv, const int* __restrict__ rs,
                                              const int* __restrict__ dg, const int* __restrict__ csr,
                                              const float* __restrict__ scale, const float* __restrict__ shift,
                                              const float* __restrict__ b3, const float* __restrict__ xres) {
    constexpr int FB = F / 64;  // feats per lane (4 or 8)
    const int i = blockIdx.x;
    const int tid = threadIdx.x;
    const int sl = tid >> 6;      // wave/slice 0..3
    const int lane = tid & 63;
    const int start = rs[i], cnt = dg[i];
    const float di = dinv[i];

    __shared__ int   s_idx[64];
    __shared__ float s_w[64];
    __shared__ float red[4][F];

    float sc[FB], sh[FB];
    if constexpr (MODE == 1) {
        #pragma unroll
        for (int k = 0; k < FB; k++) {
            sc[k] = scale[lane * FB + k];
            sh[k] = shift[lane * FB + k];
        }
    }

    float acc[FB];
    #pragma unroll
    for (int k = 0; k < FB; k++) acc[k] = 0.f;

    auto gadd = [&](int row, float wgt) {
        float v[FB];
        if constexpr (FB == 4) {
            uint2 p = *(const uint2*)(X + (size_t)row * F + lane * 4);
            v[0] = bflo(p.x); v[1] = bfhi(p.x);
            v[2] = bflo(p.y); v[3] = bfhi(p.y);
        } else {
            uint4 p = *(const uint4*)(X + (size_t)row * F + lane * 8);
            v[0] = bflo(p.x); v[1] = bfhi(p.x);
            v[2] = bflo(p.y); v[3] = bfhi(p.y);
            v[4] = bflo(p.z); v[5] = bfhi(p.z);
            v[6] = bflo(p.w); v[7] = bfhi(p.w);
        }
        #pragma unroll
        for (int k = 0; k < FB; k++) {
            if constexpr (MODE == 1) v[k] = fmaxf(fmaf(v[k], sc[k], sh[k]), 0.f);
            acc[k] = fmaf(v[k], wgt, acc[k]);
        }
    };

    if (sl == 0) gadd(i, di);  // self-loop term (weight di; overall *di applied at the end)

    for (int base = 0; base < cnt; base += 64) {
        const int m = min(64, cnt - base);
        __syncthreads();
        if (tid < m) {
            int s = csr[start + base + tid];
            s_idx[tid] = s;
            s_w[tid] = dinv[s];
        }
        __syncthreads();
        #pragma unroll 2
        for (int jj = sl; jj < m; jj += 4)
            gadd(s_idx[jj], s_w[jj]);
    }

    #pragma unroll
    for (int k = 0; k < FB; k++) red[sl][lane * FB + k] = acc[k];
    __syncthreads();

    if constexpr (MODE == 2) {
        // F == 256, one f32 feat per thread
        const int f = tid;
        float v = red[0][f] + red[1][f] + red[2][f] + red[3][f];
        Yf[(size_t)i * 256 + f] = v * di + b3[f] + xres[(size_t)i * 256 + f];
    } else {
        if (tid < F / 2) {
            const int f0 = tid * 2;
            float v0 = (red[0][f0] + red[1][f0] + red[2][f0] + red[3][f0]) * di;
            float v1 = (red[0][f0 + 1] + red[1][f0 + 1] + red[2][f0 + 1] + red[3][f0 + 1]) * di;
            *(u32*)(Y + (size_t)i * F + f0) = (u32)f2bf(v0) | ((u32)f2bf(v1) << 16);
        }
    }
}

// ---------------- bf16 MFMA GEMM: C[M][F] = A[M][K] @ Wt[F][K]^T (+bias f32, +col stats) ----
// 128x128 tile, BK=32, 4 waves each 64x64 (4x4 of 16x16x32 MFMA). C bf16 out.

template <bool STATS, bool BIAS>
__global__ __launch_bounds__(256) void gemm_k(const u16* __restrict__ A, const u16* __restrict__ Wt,
                                              const float* __restrict__ bias, u16* __restrict__ C,
                                              float* __restrict__ colsum, float* __restrict__ colsq,
                                              int M, int K, int F) {
    __shared__ u16 As[128 * 40];
    __shared__ u16 Bs[128 * 40];
    const int m0 = blockIdx.x * 128, f0 = blockIdx.y * 128;
    const int tid = threadIdx.x;
    const int lane = tid & 63, wave = tid >> 6;
    const int waveM = (wave >> 1) * 64, waveN = (wave & 1) * 64;
    const int lrow = tid >> 2, lch = tid & 3;

    f32x4 acc[4][4];
    const f32x4 fz = {0.f, 0.f, 0.f, 0.f};
    #pragma unroll
    for (int i = 0; i < 4; i++)
        #pragma unroll
        for (int j = 0; j < 4; j++) acc[i][j] = fz;

    const int rA0 = m0 + lrow, rA1 = m0 + 64 + lrow;
    const u16* pA0 = A + (size_t)rA0 * K + lch * 8;
    const u16* pA1 = A + (size_t)rA1 * K + lch * 8;
    const u16* pB0 = Wt + (size_t)(f0 + lrow) * K + lch * 8;
    const u16* pB1 = Wt + (size_t)(f0 + 64 + lrow) * K + lch * 8;
    u16* qA0 = &As[lrow * 40 + lch * 8];
    u16* qA1 = &As[(64 + lrow) * 40 + lch * 8];
    u16* qB0 = &Bs[lrow * 40 + lch * 8];
    u16* qB1 = &Bs[(64 + lrow) * 40 + lch * 8];
    const uint4 z4 = {0u, 0u, 0u, 0u};

    const int fm = lane & 15, fq = lane >> 4;

    for (int k0 = 0; k0 < K; k0 += 32) {
        uint4 a0 = (rA0 < M) ? *(const uint4*)(pA0 + k0) : z4;
        uint4 a1 = (rA1 < M) ? *(const uint4*)(pA1 + k0) : z4;
        uint4 b0 = *(const uint4*)(pB0 + k0);
        uint4 b1 = *(const uint4*)(pB1 + k0);
        __syncthreads();
        *(uint4*)qA0 = a0;
        *(uint4*)qA1 = a1;
        *(uint4*)qB0 = b0;
        *(uint4*)qB1 = b1;
        __syncthreads();
        bf16x8 af[4], bfr[4];
        #pragma unroll
        for (int i = 0; i < 4; i++)
            af[i] = *(const bf16x8*)&As[(waveM + i * 16 + fm) * 40 + fq * 8];
        #pragma unroll
        for (int j = 0; j < 4; j++)
            bfr[j] = *(const bf16x8*)&Bs[(waveN + j * 16 + fm) * 40 + fq * 8];
        #pragma unroll
        for (int i = 0; i < 4; i++)
            #pragma unroll
            for (int j = 0; j < 4; j++)
                acc[i][j] = __builtin_amdgcn_mfma_f32_16x16x32_bf16(af[i], bfr[j], acc[i][j], 0, 0, 0);
    }

    // C/D layout: col=lane&15, row=(lane>>4)*4+reg  [learn_hip m89/m91]
    #pragma unroll
    for (int j = 0; j < 4; j++) {
        const int col = f0 + waveN + j * 16 + fm;
        const float bcol = BIAS ? bias[col] : 0.f;
        float s = 0.f, s2 = 0.f;
        #pragma unroll
        for (int i = 0; i < 4; i++) {
            const int rb = m0 + waveM + i * 16 + fq * 4;
            #pragma unroll
            for (int r = 0; r < 4; r++) {
                const int row = rb + r;
                if (row < M) {
                    float v = acc[i][j][r] + bcol;
                    C[(size_t)row * F + col] = f2bf(v);
                    if (STATS) { s += v; s2 += v * v; }
                }
            }
        }
        if (STATS) {
            s += __shfl_xor(s, 16);
            s += __shfl_xor(s, 32);
            s2 += __shfl_xor(s2, 16);
            s2 += __shfl_xor(s2, 32);
            if (fq == 0) {
                atomicAdd(&colsum[col], s);
                atomicAdd(&colsq[col], s2);
            }
        }
    }
}

// ---------------- BN finalize + (standalone) apply ----------------

__global__ __launch_bounds__(256) void bnfin_k(const float* __restrict__ sum, const float* __restrict__ sq,
                                               const float* __restrict__ g, const float* __restrict__ be,
                                               float* __restrict__ scale, float* __restrict__ shift,
                                               int F, float invN) {
    int f = blockIdx.x * 256 + threadIdx.x;
    if (f < F) {
        float m = sum[f] * invN;
        float v = sq[f] * invN - m * m;
        float s = rsqrtf(v + 1e-5f) * g[f];
        scale[f] = s;
        shift[f] = be[f] - m * s;
    }
}

__global__ __launch_bounds__(256) void bnrelu_k(u16* __restrict__ H, const float* __restrict__ scale,
                                                const float* __restrict__ shift, int total, int F) {
    int idx = blockIdx.x * 256 + threadIdx.x;
    int base = idx * 8;
    if (base >= total) return;
    uint4 p = *(const uint4*)(H + base);
    int col = base & (F - 1);
    u32 w[4] = {p.x, p.y, p.z, p.w};
    u32 o[4];
    #pragma unroll
    for (int q = 0; q < 4; q++) {
        float x0 = fmaxf(bflo(w[q]) * scale[col + 2 * q] + shift[col + 2 * q], 0.f);
        float x1 = fmaxf(bfhi(w[q]) * scale[col + 2 * q + 1] + shift[col + 2 * q + 1], 0.f);
        o[q] = ((u32)f2bf(x1) << 16) | (u32)f2bf(x0);
    }
    uint4 po = {o[0], o[1], o[2], o[3]};
    *(uint4*)(H + base) = po;
}

// ---------------- launch ----------------

extern "C" void kernel_launch(void* const* d_in, const int* in_sizes, int n_in,
                              void* d_out, int out_size, void* d_ws, size_t ws_size,
                              hipStream_t stream) {
    const float* x   = (const float*)d_in[0];
    const int*   ei  = (const int*)d_in[1];
    const float* W1  = (const float*)d_in[2];
    const float* b1  = (const float*)d_in[3];
    const float* pg1 = (const float*)d_in[4];
    const float* pbe1= (const float*)d_in[5];
    const float* W2  = (const float*)d_in[6];
    const float* b2  = (const float*)d_in[7];
    const float* pg2 = (const float*)d_in[8];
    const float* pbe2= (const float*)d_in[9];
    const float* W3  = (const float*)d_in[10];
    const float* b3  = (const float*)d_in[11];
    float* out = (float*)d_out;

    char* ws = (char*)d_ws;
    size_t off = 0;
    auto alloc = [&](size_t bytes) -> char* {
        char* p = ws + off;
        off += (bytes + 255) & ~(size_t)255;
        return p;
    };
    float* dinv  = (float*)alloc(NN * 4);
    int*   deg   = (int*)alloc(NN * 4);
    int*   rs    = (int*)alloc(NN * 4);
    int*   cur   = (int*)alloc(NN * 4);
    int*   bsum  = (int*)alloc(256 * 4);
    int*   csr   = (int*)alloc(NE * 4);
    float* stats = (float*)alloc(4 * 512 * 4);
    float* cs1 = stats, *cq1 = stats + 512, *cs2 = stats + 1024, *cq2 = stats + 1536;
    float* scale1 = (float*)alloc(512 * 4);
    float* shift1 = (float*)alloc(512 * 4);
    float* scale2 = (float*)alloc(512 * 4);
    float* shift2 = (float*)alloc(512 * 4);
    u16*   W1t   = (u16*)alloc((size_t)512 * 256 * 2);
    u16*   W2t   = (u16*)alloc((size_t)512 * 512 * 2);
    u16*   W3t   = (u16*)alloc((size_t)256 * 512 * 2);
    u16*   HB    = (u16*)alloc((size_t)NN * 512 * 2);   // 51.2 MB
    u16*   G3    = (u16*)alloc((size_t)NN * 256 * 2);   // 25.6 MB; doubles as XB (x cast to bf16)

    u16* XB = G3;            // bf16 x — lifetime ends before gemm3 writes G3
    u16* A1 = (u16*)d_out;   // bf16 scratch [N,256] in d_out
    u16* A2 = (u16*)d_out;   // bf16 scratch [N,512] in d_out

    const int* srcp = ei;
    const int* dstp = ei + NE;

    hipMemsetAsync(deg, 0, NN * 4, stream);
    hipMemsetAsync(stats, 0, 4 * 512 * 4, stream);

    const int nbN = (NN + 255) / 256;
    count_k<<<(NE + 255) / 256, 256, 0, stream>>>(dstp, deg, NE);
    dinv_k<<<nbN, 256, 0, stream>>>(deg, dinv, NN);
    scan1_k<<<nbN, 256, 0, stream>>>(deg, bsum, NN);
    scan2_k<<<1, 256, 0, stream>>>(bsum, nbN);
    scan3_k<<<nbN, 256, 0, stream>>>(deg, bsum, rs, cur, NN);
    fill_k<<<(NE + 255) / 256, 256, 0, stream>>>(srcp, dstp, cur, csr, NE);

    transpose_k<<<dim3(256 / 32, 512 / 32), 256, 0, stream>>>(W1, W1t, 256, 512);
    transpose_k<<<dim3(512 / 32, 512 / 32), 256, 0, stream>>>(W2, W2t, 512, 512);
    transpose_k<<<dim3(512 / 32, 256 / 32), 256, 0, stream>>>(W3, W3t, 512, 256);

    cast_k<<<NN * 256 / 8 / 256, 256, 0, stream>>>(x, XB, NN * 256);

    const int MT = (NN + 127) / 128;  // 391

    // Layer 1: A1 = Agg(XB) [bf16, d_out]; H1 = A1@W1 + b1 -> HB [bf16] + stats
    aggu_k<256, 0><<<NN, 256, 0, stream>>>(XB, A1, nullptr, dinv, rs, deg, csr,
                                           nullptr, nullptr, nullptr, nullptr);
    gemm_k<true, true><<<dim3(MT, 4), 256, 0, stream>>>(A1, W1t, b1, HB, cs1, cq1, NN, 256, 512);
    bnfin_k<<<2, 256, 0, stream>>>(cs1, cq1, pg1, pbe1, scale1, shift1, 512, 1.f / NN);

    // Layer 2: A2 = Agg(relu(bn(H1))) fused [bf16, d_out]; H2 = A2@W2 + b2 -> HB + stats
    aggu_k<512, 1><<<NN, 256, 0, stream>>>(HB, A2, nullptr, dinv, rs, deg, csr,
                                           scale1, shift1, nullptr, nullptr);
    gemm_k<true, true><<<dim3(MT, 4), 256, 0, stream>>>(A2, W2t, b2, HB, cs2, cq2, NN, 512, 512);
    bnfin_k<<<2, 256, 0, stream>>>(cs2, cq2, pg2, pbe2, scale2, shift2, 512, 1.f / NN);
    bnrelu_k<<<NN * 512 / 8 / 256, 256, 0, stream>>>(HB, scale2, shift2, NN * 512, 512);

    // Layer 3: G3 = H2@W3 [bf16, ws, overwrites XB]; out = Agg(G3) + b3 + x [f32, d_out]
    gemm_k<false, false><<<dim3(MT, 2), 256, 0, stream>>>(HB, W3t, nullptr, G3, nullptr, nullptr, NN, 512, 256);
    aggu_k<256, 2><<<NN, 256, 0, stream>>>(G3, nullptr, out, dinv, rs, deg, csr,
                                           nullptr, nullptr, b3, x);
}